// Round 7
// baseline (149.356 us; speedup 1.0000x reference)
//
#include <hip/hip_runtime.h>
#include <hip/hip_bf16.h>

#define NB 64
#define S_ 1024
#define D_ 128

typedef __attribute__((ext_vector_type(8))) short bf16x8;
typedef __attribute__((ext_vector_type(4))) float f32x4;

// Fragment-tiled layout: operands stored as 16-row x 32-k panels of 1KB,
// element (r,k) at short-offset (((k>>3)&3)*16 + (r&15))*8 + (k&7) ==
// lane*8 + j in MFMA A/B fragment order -> a wave fragment load/store is
// base + lane*16B: one coalesced 1KB transaction.

__device__ __forceinline__ unsigned short f2bf(float f) {
  __hip_bfloat16 h = __float2bfloat16(f);
  return __builtin_bit_cast(unsigned short, h);
}

__device__ __forceinline__ void async_copy16(const void* g, void* l) {
  __builtin_amdgcn_global_load_lds(
      (const __attribute__((address_space(1))) unsigned int*)g,
      (__attribute__((address_space(3))) unsigned int*)l, 16, 0, 0);
}

// ---- fused: per-batch partial stats (blocks 0..1023) + W pack (1024..3071) --
__global__ __launch_bounds__(256) void prep_kernel(
    const float* __restrict__ x, const float* __restrict__ W1,
    const float* __restrict__ W2, float2* __restrict__ part,
    unsigned short* __restrict__ W1f, unsigned short* __restrict__ W2f) {
  const int blk = blockIdx.x;
  if (blk < 1024) {
    const int b = blk >> 4, c = blk & 15, t = threadIdx.x;
    const float4* xb = (const float4*)(x + (size_t)b * (S_ * D_) + c * 8192);
    float s = 0.f, q = 0.f;
#pragma unroll
    for (int i = 0; i < 8; ++i) {
      float4 v = xb[i * 256 + t];
      s += v.x + v.y + v.z + v.w;
      q += v.x * v.x + v.y * v.y + v.z * v.z + v.w * v.w;
    }
#pragma unroll
    for (int o = 32; o > 0; o >>= 1) {
      s += __shfl_down(s, o, 64);
      q += __shfl_down(q, o, 64);
    }
    __shared__ float2 w4[4];
    const int wave = t >> 6, lane = t & 63;
    if (lane == 0) w4[wave] = make_float2(s, q);
    __syncthreads();
    if (t == 0) {
      float ss = 0.f, qq = 0.f;
#pragma unroll
      for (int i = 0; i < 4; ++i) { ss += w4[i].x; qq += w4[i].y; }
      part[blk] = make_float2(ss, qq);
    }
  } else {
    const int id = (blk - 1024) * 256 + threadIdx.x;  // 0 .. 524287
    const int perW = (S_ * S_) / 4;
    const float* src = (id < perW) ? W1 : W2;
    unsigned short* dst = (id < perW) ? W1f : W2f;
    const int i4 = (id < perW) ? id : id - perW;
    const int flat = i4 * 4;
    const int trow = flat >> 10;       // t
    const int scol = flat & 1023;      // s (multiple of 4)
    float4 v = ((const float4*)src)[i4];
    ushort4 o;
    o.x = f2bf((scol + 0 <= trow) ? v.x : 0.f);
    o.y = f2bf((scol + 1 <= trow) ? v.y : 0.f);
    o.z = f2bf((scol + 2 <= trow) ? v.z : 0.f);
    o.w = f2bf((scol + 3 <= trow) ? v.w : 0.f);
    const size_t fa = ((size_t)(trow >> 4) * 32 + (scol >> 5)) * 512 +
                      ((scol >> 3) & 3) * 128 + (trow & 15) * 8 + (scol & 4);
    *(ushort4*)(dst + fa) = o;
  }
}

// ------- normalize + write hT in fragment-tiled layout (B-operand) ----------
__global__ __launch_bounds__(256) void norm_t_kernel(const float* __restrict__ x,
                                                     const float* __restrict__ w,
                                                     const float* __restrict__ bb,
                                                     const float2* __restrict__ part,
                                                     unsigned short* __restrict__ hTf) {
  __shared__ unsigned short lds[128 * 72];   // [d][s-tile 64 + 8 pad]
  const int blk = blockIdx.x;
  const int b = blk >> 4;
  const int s0 = (blk & 15) * 64;
  const int t = threadIdx.x;
  const int wave = t >> 6, lane = t & 63;
  const int quad = lane >> 4, l16 = lane & 15;
  float sum = 0.f, sumq = 0.f;
#pragma unroll
  for (int i = 0; i < 16; ++i) {
    float2 p = part[b * 16 + i];
    sum += p.x; sumq += p.y;
  }
  const float inv = 1.0f / (S_ * D_);
  const float mu = sum * inv;
  const float rs = rsqrtf(sumq * inv - mu * mu + 1e-5f);

  const float4* xb = (const float4*)(x + ((size_t)b * S_ + s0) * D_);
  const float4* wb = (const float4*)(w + (size_t)s0 * D_);
  const float4* bv4 = (const float4*)(bb + (size_t)s0 * D_);
#pragma unroll
  for (int r = 0; r < 8; ++r) {
    const int f = r * 256 + t;
    const int srow = f >> 5;
    const int c4 = f & 31;
    float4 xv = xb[f];
    float4 wv = wb[f];
    float4 bvv = bv4[f];
    float h0 = (xv.x - mu) * rs * wv.x + bvv.x;
    float h1 = (xv.y - mu) * rs * wv.y + bvv.y;
    float h2 = (xv.z - mu) * rs * wv.z + bvv.z;
    float h3 = (xv.w - mu) * rs * wv.w + bvv.w;
    const int d0 = c4 * 4;
    lds[(d0 + 0) * 72 + srow] = f2bf(h0);
    lds[(d0 + 1) * 72 + srow] = f2bf(h1);
    lds[(d0 + 2) * 72 + srow] = f2bf(h2);
    lds[(d0 + 3) * 72 + srow] = f2bf(h3);
  }
  __syncthreads();
  unsigned short* outp = hTf + (size_t)b * (D_ * S_);
  const int cg0 = (blk & 15) * 2;
#pragma unroll
  for (int ff = 0; ff < 4; ++ff) {
    const int f = wave * 4 + ff;       // 16 fragments per block
    const int p = f >> 1, cl = f & 1;
    const int d = p * 16 + l16;
    const int sb = cl * 32 + quad * 8;
    bf16x8 v = *(const bf16x8*)(lds + d * 72 + sb);
    *(bf16x8*)(outp + ((size_t)p * 32 + cg0 + cl) * 512 + lane * 8) = v;
  }
}

// --------- causal batched GEMM: paired M-tiles, equal-work blocks ------------
// Block = (pair p, batch b); processes tile mt=p then mt=15-p sequentially.
// Total k-chunks per block = 2(p+1) + 2(16-p) = 34 for EVERY block -> no tail
// imbalance (R5 showed 25% occupancy from unequal block lengths). Grid 512 =
// 2 equal blocks/CU. Within a phase: A (4x wave reuse) staged per 256-k panel
// into LDS via global_load_lds then ds_read_b128; B direct global->VGPR 1KB
// coalesced with depth-4 rolling prefetch. Barrier before each panel staging
// also guards phase-0 epilogue's LDS reuse.
template <bool HSWISH>
__global__ __launch_bounds__(256, 2) void gemm_causal(
    const unsigned short* __restrict__ Af, const unsigned short* __restrict__ Bf,
    unsigned short* __restrict__ Uf, const float* __restrict__ Xres,
    float* __restrict__ Out) {
  __shared__ __align__(16) unsigned short ldsA[16384];   // 32 KB

  const int t = threadIdx.x;
  const int wave = t >> 6, lane = t & 63;
  const int quad = lane >> 4, l16 = lane & 15;

  const int bi = blockIdx.x;           // 0..511
  const int xcd = bi & 7;
  const int rest = bi >> 3;            // 0..63
  const int b = xcd * 8 + (rest & 7);
  const int pair = rest >> 3;          // 0..7

  const unsigned short* Bb = Bf + (size_t)b * (D_ * S_);

  for (int ph = 0; ph < 2; ++ph) {
    const int mt = ph ? (15 - pair) : pair;
    const int row0 = mt * 64;
    const int cend = 2 * (mt + 1);     // active 32-k chunks (even, 2..32)
    const int npan = (cend + 7) >> 3;  // 256-k panels
    const unsigned short* Ab = Af + (size_t)mt * 4 * 32 * 512;

    f32x4 acc[4][2] = {};
    bf16x8 Bp[4][2];
#pragma unroll
    for (int g = 0; g < 4; ++g) {
      const int gg = (g < cend) ? g : 0;
#pragma unroll
      for (int jj = 0; jj < 2; ++jj)
        Bp[g][jj] = *(const bf16x8*)(Bb + ((size_t)(wave * 2 + jj) * 32 + gg) * 512 + lane * 8);
    }

    for (int p = 0; p < npan; ++p) {
      __syncthreads();                 // LDS safe to overwrite
#pragma unroll
      for (int jc = 0; jc < 8; ++jc) { // stage 32KB: A panels [mt*4+iw][p*8+cc]
        const int flat16 = jc * 256 + t;
        const int iw = flat16 >> 9;
        const int cc = (flat16 >> 6) & 7;
        const int li = flat16 & 63;
        async_copy16(Ab + ((size_t)iw * 32 + p * 8 + cc) * 512 + li * 8,
                     ldsA + flat16 * 8);
      }
      __syncthreads();                 // drains vmcnt; A panel ready
#pragma unroll
      for (int c = 0; c < 8; ++c) {
        const int g = p * 8 + c;
        if (g < cend) {
          bf16x8 af[4];
#pragma unroll
          for (int i = 0; i < 4; ++i)
            af[i] = *(const bf16x8*)(ldsA + i * 4096 + c * 512 + lane * 8);
#pragma unroll
          for (int i = 0; i < 4; ++i)
#pragma unroll
            for (int jj = 0; jj < 2; ++jj)
              acc[i][jj] = __builtin_amdgcn_mfma_f32_16x16x32_bf16(
                  af[i], Bp[c & 3][jj], acc[i][jj], 0, 0, 0);
          const int gn = (g + 4 < cend) ? (g + 4) : 0;
#pragma unroll
          for (int jj = 0; jj < 2; ++jj)
            Bp[c & 3][jj] = *(const bf16x8*)(
                Bb + ((size_t)(wave * 2 + jj) * 32 + gn) * 512 + lane * 8);
        }
      }
    }

    if (HSWISH) {
      __syncthreads();                 // done reading ldsA; reuse for transpose
      unsigned short* ldsT = ldsA;     // [d][t 64 + 8 pad] = 18KB of 32KB
#pragma unroll
      for (int i = 0; i < 4; ++i)
#pragma unroll
        for (int jj = 0; jj < 2; ++jj) {
          ushort4 pk;
          float v0 = acc[i][jj][0], v1 = acc[i][jj][1], v2 = acc[i][jj][2], v3 = acc[i][jj][3];
          pk.x = f2bf(v0 * fminf(fmaxf(v0 + 3.f, 0.f), 6.f) * (1.f / 6.f));
          pk.y = f2bf(v1 * fminf(fmaxf(v1 + 3.f, 0.f), 6.f) * (1.f / 6.f));
          pk.z = f2bf(v2 * fminf(fmaxf(v2 + 3.f, 0.f), 6.f) * (1.f / 6.f));
          pk.w = f2bf(v3 * fminf(fmaxf(v3 + 3.f, 0.f), 6.f) * (1.f / 6.f));
          const int n = wave * 32 + jj * 16 + l16;  // d
          const int m0 = i * 16 + quad * 4;         // t within 64-tile
          *(ushort4*)(ldsT + n * 72 + m0) = pk;
        }
      __syncthreads();
      unsigned short* gU = Uf + (size_t)b * (D_ * S_);
#pragma unroll
      for (int ff = 0; ff < 4; ++ff) {
        const int f = wave * 4 + ff;
        const int p2 = f >> 1, cl = f & 1;
        const int d = p2 * 16 + l16;
        const int tb = cl * 32 + quad * 8;
        bf16x8 v = *(const bf16x8*)(ldsT + d * 72 + tb);
        *(bf16x8*)(gU + ((size_t)p2 * 32 + mt * 2 + cl) * 512 + lane * 8) = v;
      }
    } else {
      float* gO = Out + (size_t)b * S_ * D_;
      const float* gX = Xres + (size_t)b * S_ * D_;
#pragma unroll
      for (int i = 0; i < 4; ++i) {
        const int mrow0 = row0 + i * 16 + quad * 4;
#pragma unroll
        for (int jj = 0; jj < 2; ++jj) {
          const int col = wave * 32 + jj * 16 + l16;
#pragma unroll
          for (int r = 0; r < 4; ++r) {
            const int addr = (mrow0 + r) * D_ + col;
            gO[addr] = gX[addr] + acc[i][jj][r];
          }
        }
      }
    }
  }
}

extern "C" void kernel_launch(void* const* d_in, const int* in_sizes, int n_in,
                              void* d_out, int out_size, void* d_ws, size_t ws_size,
                              hipStream_t stream) {
  const float* x = (const float*)d_in[0];
  const float* ln_w = (const float*)d_in[1];
  const float* ln_b = (const float*)d_in[2];
  const float* W1 = (const float*)d_in[3];
  const float* W2 = (const float*)d_in[4];
  float* out = (float*)d_out;

  char* ws = (char*)d_ws;
  float2* part = (float2*)ws;                                // 8 KiB
  unsigned short* W1f = (unsigned short*)(ws + 16384);       // 2 MiB
  unsigned short* W2f = W1f + (size_t)S_ * S_;               // 2 MiB
  unsigned short* hTf = W2f + (size_t)S_ * S_;               // 16 MiB
  unsigned short* uTf = hTf + (size_t)NB * D_ * S_;          // 16 MiB

  prep_kernel<<<3072, 256, 0, stream>>>(x, W1, W2, part, W1f, W2f);
  norm_t_kernel<<<NB * 16, 256, 0, stream>>>(x, ln_w, ln_b, part, hTf);
  gemm_causal<true><<<512, 256, 0, stream>>>(W1f, hTf, uTf, nullptr, nullptr);
  gemm_causal<false><<<512, 256, 0, stream>>>(W2f, uTf, nullptr, x, out);
}

// Round 8
// 140.358 us; speedup vs baseline: 1.0641x; 1.0641x over previous
//
#include <hip/hip_runtime.h>
#include <hip/hip_bf16.h>

#define NB 64
#define S_ 1024
#define D_ 128

typedef __attribute__((ext_vector_type(8))) short bf16x8;
typedef __attribute__((ext_vector_type(4))) float f32x4;

// Fragment-tiled layout: operands stored as 16-row x 32-k panels of 1KB,
// element (r,k) at short-offset (((k>>3)&3)*16 + (r&15))*8 + (k&7) ==
// lane*8 + j in MFMA A/B fragment order -> a wave fragment load/store is
// base + lane*16B: one coalesced 1KB transaction.

__device__ __forceinline__ unsigned short f2bf(float f) {
  __hip_bfloat16 h = __float2bfloat16(f);
  return __builtin_bit_cast(unsigned short, h);
}

__device__ __forceinline__ void async_copy16(const void* g, void* l) {
  __builtin_amdgcn_global_load_lds(
      (const __attribute__((address_space(1))) unsigned int*)g,
      (__attribute__((address_space(3))) unsigned int*)l, 16, 0, 0);
}

// ---- fused: per-batch partial stats (blocks 0..1023) + W pack (1024..3071) --
__global__ __launch_bounds__(256) void prep_kernel(
    const float* __restrict__ x, const float* __restrict__ W1,
    const float* __restrict__ W2, float2* __restrict__ part,
    unsigned short* __restrict__ W1f, unsigned short* __restrict__ W2f) {
  const int blk = blockIdx.x;
  if (blk < 1024) {
    const int b = blk >> 4, c = blk & 15, t = threadIdx.x;
    const float4* xb = (const float4*)(x + (size_t)b * (S_ * D_) + c * 8192);
    float s = 0.f, q = 0.f;
#pragma unroll
    for (int i = 0; i < 8; ++i) {
      float4 v = xb[i * 256 + t];
      s += v.x + v.y + v.z + v.w;
      q += v.x * v.x + v.y * v.y + v.z * v.z + v.w * v.w;
    }
#pragma unroll
    for (int o = 32; o > 0; o >>= 1) {
      s += __shfl_down(s, o, 64);
      q += __shfl_down(q, o, 64);
    }
    __shared__ float2 w4[4];
    const int wave = t >> 6, lane = t & 63;
    if (lane == 0) w4[wave] = make_float2(s, q);
    __syncthreads();
    if (t == 0) {
      float ss = 0.f, qq = 0.f;
#pragma unroll
      for (int i = 0; i < 4; ++i) { ss += w4[i].x; qq += w4[i].y; }
      part[blk] = make_float2(ss, qq);
    }
  } else {
    const int id = (blk - 1024) * 256 + threadIdx.x;  // 0 .. 524287
    const int perW = (S_ * S_) / 4;
    const float* src = (id < perW) ? W1 : W2;
    unsigned short* dst = (id < perW) ? W1f : W2f;
    const int i4 = (id < perW) ? id : id - perW;
    const int flat = i4 * 4;
    const int trow = flat >> 10;       // t
    const int scol = flat & 1023;      // s (multiple of 4)
    float4 v = ((const float4*)src)[i4];
    ushort4 o;
    o.x = f2bf((scol + 0 <= trow) ? v.x : 0.f);
    o.y = f2bf((scol + 1 <= trow) ? v.y : 0.f);
    o.z = f2bf((scol + 2 <= trow) ? v.z : 0.f);
    o.w = f2bf((scol + 3 <= trow) ? v.w : 0.f);
    const size_t fa = ((size_t)(trow >> 4) * 32 + (scol >> 5)) * 512 +
                      ((scol >> 3) & 3) * 128 + (trow & 15) * 8 + (scol & 4);
    *(ushort4*)(dst + fa) = o;
  }
}

// ------- normalize + write hT in fragment-tiled layout (B-operand) ----------
__global__ __launch_bounds__(256) void norm_t_kernel(const float* __restrict__ x,
                                                     const float* __restrict__ w,
                                                     const float* __restrict__ bb,
                                                     const float2* __restrict__ part,
                                                     unsigned short* __restrict__ hTf) {
  __shared__ unsigned short lds[128 * 72];   // [d][s-tile 64 + 8 pad]
  const int blk = blockIdx.x;
  const int b = blk >> 4;
  const int s0 = (blk & 15) * 64;
  const int t = threadIdx.x;
  const int wave = t >> 6, lane = t & 63;
  const int quad = lane >> 4, l16 = lane & 15;
  float sum = 0.f, sumq = 0.f;
#pragma unroll
  for (int i = 0; i < 16; ++i) {
    float2 p = part[b * 16 + i];
    sum += p.x; sumq += p.y;
  }
  const float inv = 1.0f / (S_ * D_);
  const float mu = sum * inv;
  const float rs = rsqrtf(sumq * inv - mu * mu + 1e-5f);

  const float4* xb = (const float4*)(x + ((size_t)b * S_ + s0) * D_);
  const float4* wb = (const float4*)(w + (size_t)s0 * D_);
  const float4* bv4 = (const float4*)(bb + (size_t)s0 * D_);
#pragma unroll
  for (int r = 0; r < 8; ++r) {
    const int f = r * 256 + t;
    const int srow = f >> 5;
    const int c4 = f & 31;
    float4 xv = xb[f];
    float4 wv = wb[f];
    float4 bvv = bv4[f];
    float h0 = (xv.x - mu) * rs * wv.x + bvv.x;
    float h1 = (xv.y - mu) * rs * wv.y + bvv.y;
    float h2 = (xv.z - mu) * rs * wv.z + bvv.z;
    float h3 = (xv.w - mu) * rs * wv.w + bvv.w;
    const int d0 = c4 * 4;
    lds[(d0 + 0) * 72 + srow] = f2bf(h0);
    lds[(d0 + 1) * 72 + srow] = f2bf(h1);
    lds[(d0 + 2) * 72 + srow] = f2bf(h2);
    lds[(d0 + 3) * 72 + srow] = f2bf(h3);
  }
  __syncthreads();
  unsigned short* outp = hTf + (size_t)b * (D_ * S_);
  const int cg0 = (blk & 15) * 2;
#pragma unroll
  for (int ff = 0; ff < 4; ++ff) {
    const int f = wave * 4 + ff;       // 16 fragments per block
    const int p = f >> 1, cl = f & 1;
    const int d = p * 16 + l16;
    const int sb = cl * 32 + quad * 8;
    bf16x8 v = *(const bf16x8*)(lds + d * 72 + sb);
    *(bf16x8*)(outp + ((size_t)p * 32 + cg0 + cl) * 512 + lane * 8) = v;
  }
}

// ---- causal batched GEMM: double-buffered LDS A, direct-prefetched B --------
// BM=64 (t), BN=128 (d); wave owns 64m x 32n. Grid 1024 = 4 blocks/CU (R6
// decode: co-resident mts balanced, batch per XCD). A staged in ping-pong
// 16KB buffers of 4 k-chunks via global_load_lds: staging for panel p+1 is
// issued right after the barrier, overlapping compute of panel p, so the
// end-of-iteration vmcnt drain waits only on the residue. B: direct
// global->VGPR 1KB coalesced, depth-4 rolling prefetch.
template <bool HSWISH>
__global__ __launch_bounds__(256, 4) void gemm_causal(
    const unsigned short* __restrict__ Af, const unsigned short* __restrict__ Bf,
    unsigned short* __restrict__ Uf, const float* __restrict__ Xres,
    float* __restrict__ Out) {
  __shared__ __align__(16) unsigned short ldsA[16384];   // 2 x 16KB

  const int t = threadIdx.x;
  const int wave = t >> 6, lane = t & 63;
  const int quad = lane >> 4, l16 = lane & 15;

  const int bi = blockIdx.x;
  const int xcd = bi & 7;
  const int slot = bi >> 3;            // 0..127
  const int b = xcd * 8 + (slot & 7);
  const int j = slot >> 3;             // 0..15
  const int mt = (j < 8) ? j : (j ^ 3);
  const int row0 = mt * 64;

  const int cend = 2 * (mt + 1);       // active 32-k chunks (even, 2..32)
  const int npan = (cend + 3) >> 2;    // 128-k panels of 4 chunks

  const unsigned short* Ab = Af + (size_t)mt * 4 * 32 * 512;
  const unsigned short* Bb = Bf + (size_t)b * (D_ * S_);

  f32x4 acc[4][2] = {};
  bf16x8 Bp[4][2];
#pragma unroll
  for (int g = 0; g < 4; ++g) {
    const int gg = (g < cend) ? g : 0;
#pragma unroll
    for (int jj = 0; jj < 2; ++jj)
      Bp[g][jj] = *(const bf16x8*)(Bb + ((size_t)(wave * 2 + jj) * 32 + gg) * 512 + lane * 8);
  }

  // stage panel 0 into buffer 0
#pragma unroll
  for (int jc = 0; jc < 4; ++jc) {
    const int flat16 = jc * 256 + t;   // 0..1023 (16B units)
    const int iw = flat16 >> 8;        // 0..3
    const int cc = (flat16 >> 6) & 3;  // 0..3
    const int li = flat16 & 63;
    async_copy16(Ab + ((size_t)iw * 32 + cc) * 512 + li * 8, ldsA + flat16 * 8);
  }
  __syncthreads();                     // panel 0 ready

  for (int p = 0; p < npan; ++p) {
    const int s = p & 1;
    if (p + 1 < npan) {                // stage next panel into other buffer;
      const int sn = (p + 1) & 1;      // overlaps with compute below
#pragma unroll
      for (int jc = 0; jc < 4; ++jc) {
        const int flat16 = jc * 256 + t;
        const int iw = flat16 >> 8;
        const int cc = (flat16 >> 6) & 3;
        const int li = flat16 & 63;
        async_copy16(Ab + ((size_t)iw * 32 + (p + 1) * 4 + cc) * 512 + li * 8,
                     ldsA + (size_t)sn * 8192 + flat16 * 8);
      }
    }
#pragma unroll
    for (int c = 0; c < 4; ++c) {
      const int g = p * 4 + c;
      if (g < cend) {
        bf16x8 af[4];
#pragma unroll
        for (int i = 0; i < 4; ++i)
          af[i] = *(const bf16x8*)(ldsA + (size_t)s * 8192 + i * 2048 + c * 512 + lane * 8);
#pragma unroll
        for (int i = 0; i < 4; ++i)
#pragma unroll
          for (int jj = 0; jj < 2; ++jj)
            acc[i][jj] = __builtin_amdgcn_mfma_f32_16x16x32_bf16(
                af[i], Bp[c & 3][jj], acc[i][jj], 0, 0, 0);
        const int gn = (g + 4 < cend) ? (g + 4) : 0;
#pragma unroll
        for (int jj = 0; jj < 2; ++jj)
          Bp[c & 3][jj] = *(const bf16x8*)(
              Bb + ((size_t)(wave * 2 + jj) * 32 + gn) * 512 + lane * 8);
      }
    }
    __syncthreads();                   // next panel staged + this buffer free
  }

  if (HSWISH) {
    unsigned short* ldsT = ldsA;       // [d][t 64 + 8 pad] = 18KB of 32KB
#pragma unroll
    for (int i = 0; i < 4; ++i)
#pragma unroll
      for (int jj = 0; jj < 2; ++jj) {
        ushort4 pk;
        float v0 = acc[i][jj][0], v1 = acc[i][jj][1], v2 = acc[i][jj][2], v3 = acc[i][jj][3];
        pk.x = f2bf(v0 * fminf(fmaxf(v0 + 3.f, 0.f), 6.f) * (1.f / 6.f));
        pk.y = f2bf(v1 * fminf(fmaxf(v1 + 3.f, 0.f), 6.f) * (1.f / 6.f));
        pk.z = f2bf(v2 * fminf(fmaxf(v2 + 3.f, 0.f), 6.f) * (1.f / 6.f));
        pk.w = f2bf(v3 * fminf(fmaxf(v3 + 3.f, 0.f), 6.f) * (1.f / 6.f));
        const int n = wave * 32 + jj * 16 + l16;    // d
        const int m0 = i * 16 + quad * 4;           // t within 64-tile
        *(ushort4*)(ldsT + n * 72 + m0) = pk;
      }
    __syncthreads();
    unsigned short* gU = Uf + (size_t)b * (D_ * S_);
#pragma unroll
    for (int ff = 0; ff < 4; ++ff) {
      const int f = wave * 4 + ff;
      const int p2 = f >> 1, cl = f & 1;
      const int d = p2 * 16 + l16;
      const int tb = cl * 32 + quad * 8;
      bf16x8 v = *(const bf16x8*)(ldsT + d * 72 + tb);
      *(bf16x8*)(gU + ((size_t)p2 * 32 + mt * 2 + cl) * 512 + lane * 8) = v;
    }
  } else {
    float* gO = Out + (size_t)b * S_ * D_;
    const float* gX = Xres + (size_t)b * S_ * D_;
#pragma unroll
    for (int i = 0; i < 4; ++i) {
      const int mrow0 = row0 + i * 16 + quad * 4;
#pragma unroll
      for (int jj = 0; jj < 2; ++jj) {
        const int col = wave * 32 + jj * 16 + l16;
#pragma unroll
        for (int r = 0; r < 4; ++r) {
          const int addr = (mrow0 + r) * D_ + col;
          gO[addr] = gX[addr] + acc[i][jj][r];
        }
      }
    }
  }
}

extern "C" void kernel_launch(void* const* d_in, const int* in_sizes, int n_in,
                              void* d_out, int out_size, void* d_ws, size_t ws_size,
                              hipStream_t stream) {
  const float* x = (const float*)d_in[0];
  const float* ln_w = (const float*)d_in[1];
  const float* ln_b = (const float*)d_in[2];
  const float* W1 = (const float*)d_in[3];
  const float* W2 = (const float*)d_in[4];
  float* out = (float*)d_out;

  char* ws = (char*)d_ws;
  float2* part = (float2*)ws;                                // 8 KiB
  unsigned short* W1f = (unsigned short*)(ws + 16384);       // 2 MiB
  unsigned short* W2f = W1f + (size_t)S_ * S_;               // 2 MiB
  unsigned short* hTf = W2f + (size_t)S_ * S_;               // 16 MiB
  unsigned short* uTf = hTf + (size_t)NB * D_ * S_;          // 16 MiB

  prep_kernel<<<3072, 256, 0, stream>>>(x, W1, W2, part, W1f, W2f);
  norm_t_kernel<<<NB * 16, 256, 0, stream>>>(x, ln_w, ln_b, part, hTf);
  gemm_causal<true><<<1024, 256, 0, stream>>>(W1f, hTf, uTf, nullptr, nullptr);
  gemm_causal<false><<<1024, 256, 0, stream>>>(W2f, uTf, nullptr, x, out);
}